// Round 9
// baseline (130.551 us; speedup 1.0000x reference)
//
#include <hip/hip_runtime.h>
#include <math.h>

// Problem constants (from reference setup_inputs)
#define NQ 2048
#define NB 8192
#define DIM 32

#define LOG2E 1.44269504088896340736f

typedef _Float16 half8 __attribute__((ext_vector_type(8)));
typedef float    f32x4 __attribute__((ext_vector_type(4)));

// ---------------- workspace layout (bytes) ----------------
// Partial sums, written by plain stores (every slot covered -> no init needed,
// no atomics, no fences). Layout [chunk][q], chunk = blockIdx.x*4 + wave.
#define NCHUNK 32                       // 8 blocks.x * 4 waves
#define WS_PSK  0                       // NCHUNK*NQ f32 = 262144 B
#define WS_PSKY (NCHUNK * NQ * 4)       // NCHUNK*NQ f32

// Fused main: grid (8, 128) = 1024 blocks (4/CU), 256 threads (4 waves).
// Wave task: one 16-query tile x 256-bg chunk = 16 MFMA tiles of 16 bgs.
// All operand prep (f32 -> f16 rounding, w-scaling, row norms) is done
// in-kernel from the raw inputs -- no separate pre pass, no f16 staging
// arrays, no acc zeroing.
//   d2 = q2 + b2 - 2*dot computed as MFMA(A=rounded(xq*w),
//        B=-2*rounded(xb*w) [exact f16 scale], C=q2+b2).
// Norms q2/b2 are computed FROM THE ROUNDED f16 VALUES so d2 = ||a-b||^2
// exactly in f16-representation space (no cancellation mismatch).
// C/D layout (16x16x32_f16): col = lane&15 (bg), row = (lane>>4)*4+reg (q).
//
// R5 lesson: no __threadfence / fused finalize -- per-block agent-scope
// fences emit buffer_wbl2/inv and thrash L2 for all in-flight blocks.
// R7 lesson: no hand-built r double-buffer -- the fully-unrolled loop already
// lets the scheduler hoist loads (explicit prefetch was neutral).
// R8 BUG (fixed): b2 fill ran 4 passes = 64 rows, but the wave owns 256 rows
// -- iterations it>=4 read uninitialized LDS. Need BG_PER_WAVE/16 = 16 passes.
#define BT_PER_WAVE 16
#define BG_PER_WAVE (BT_PER_WAVE * 16)   // 256

__global__ __launch_bounds__(256) void relnw_main(
    const float* __restrict__ xb,      // (NB, DIM)
    const float* __restrict__ yb,      // (NB,)
    const float* __restrict__ xq,      // (NQ, DIM)
    const float* __restrict__ r,       // (NQ, NB)
    const float* __restrict__ sigma,   // (1,)
    const float* __restrict__ rscale,  // (1,)
    const float* __restrict__ w,       // (DIM,)
    float* __restrict__ psk,           // [NCHUNK][NQ]
    float* __restrict__ psky)          // [NCHUNK][NQ]
{
    __shared__ float b2l[4][BG_PER_WAVE];   // per-wave bg-row norms (4 KB)

    const int tid  = threadIdx.x;
    const int lane = tid & 63;
    const int wid  = tid >> 6;
    const int m    = lane & 15;   // A row (query) / B col (bg) / C col (bg)
    const int quad = lane >> 4;   // 0..3

    const int q0     = blockIdx.y * 16;
    const int chunk  = blockIdx.x * 4 + wid;
    const int bstart = chunk * BG_PER_WAVE;

    const float c1 = -LOG2E / sigma[0];   // coeff on dist (log2 space)
    const float c2 =  LOG2E * rscale[0];  // coeff on r

    // w slices: wq = w[quad*8..+8] (for afrag/bfrag), wc = w[(lane&3)*8..+8]
    // (for the 4-lanes-per-row norm passes).
    float wq[8], wc[8];
    {
        const float4 a = ((const float4*)(w + quad * 8))[0];
        const float4 b = ((const float4*)(w + quad * 8))[1];
        wq[0]=a.x; wq[1]=a.y; wq[2]=a.z; wq[3]=a.w;
        wq[4]=b.x; wq[5]=b.y; wq[6]=b.z; wq[7]=b.w;
        const int p = lane & 3;
        const float4 c = ((const float4*)(w + p * 8))[0];
        const float4 d = ((const float4*)(w + p * 8))[1];
        wc[0]=c.x; wc[1]=c.y; wc[2]=c.z; wc[3]=c.w;
        wc[4]=d.x; wc[5]=d.y; wc[6]=d.z; wc[7]=d.w;
    }

    // A fragment: row q0+m, k-slice quad*8..+8, rounded(xq*w)
    half8 afrag;
    {
        const float* row = xq + (size_t)(q0 + m) * DIM + quad * 8;
        const float4 a = ((const float4*)row)[0];
        const float4 b = ((const float4*)row)[1];
        const float v[8] = {a.x,a.y,a.z,a.w,b.x,b.y,b.z,b.w};
#pragma unroll
        for (int c = 0; c < 8; ++c) afrag[c] = (_Float16)(v[c] * wq[c]);
    }

    // q2 for all 16 block queries, in-wave: 4 lanes/row x 16 rows (1 pass).
    float q2r[4];
    {
        const int p = lane & 3, rw = lane >> 2;       // rw = 0..15
        const float* src = xq + (size_t)(q0 + rw) * DIM + p * 8;
        const float4 a = ((const float4*)src)[0];
        const float4 b = ((const float4*)src)[1];
        const float v[8] = {a.x,a.y,a.z,a.w,b.x,b.y,b.z,b.w};
        float s = 0.f;
#pragma unroll
        for (int c = 0; c < 8; ++c) {
            float th = (float)(_Float16)(v[c] * wc[c]);
            s = fmaf(th, th, s);
        }
        s += __shfl_xor(s, 1, 64);
        s += __shfl_xor(s, 2, 64);
        // full row-sum now lives at lanes rw*4..rw*4+3; grab rows quad*4+g
#pragma unroll
        for (int g = 0; g < 4; ++g)
            q2r[g] = __shfl(s, (quad * 4 + g) * 4, 64);
    }

    // b2 for this wave's 256 bg rows -> LDS. 16 rows/pass x 16 passes.
    {
        const int p = lane & 3, rw = lane >> 2;
#pragma unroll
        for (int pass = 0; pass < BG_PER_WAVE / 16; ++pass) {   // 16 passes
            const int lrow = pass * 16 + rw;                    // 0..255
            const float* src = xb + (size_t)(bstart + lrow) * DIM + p * 8;
            const float4 a = ((const float4*)src)[0];
            const float4 b = ((const float4*)src)[1];
            const float v[8] = {a.x,a.y,a.z,a.w,b.x,b.y,b.z,b.w};
            float s = 0.f;
#pragma unroll
            for (int c = 0; c < 8; ++c) {
                float th = (float)(_Float16)(v[c] * wc[c]);
                s = fmaf(th, th, s);
            }
            s += __shfl_xor(s, 1, 64);
            s += __shfl_xor(s, 2, 64);
            if (p == 0) b2l[wid][lrow] = s;
        }
    }
    __syncthreads();   // one cheap barrier covers the LDS write->read dep

    // r row-base pointers: every in-loop r load is base + compile-time offset
    const float* rbase[4];
#pragma unroll
    for (int g = 0; g < 4; ++g)
        rbase[g] = r + (size_t)(q0 + quad * 4 + g) * NB + bstart + m;

    float sk[4]  = {0.f, 0.f, 0.f, 0.f};
    float sky[4] = {0.f, 0.f, 0.f, 0.f};

#pragma unroll
    for (int it = 0; it < BT_PER_WAVE; ++it) {
        const int bc = bstart + it * 16 + m;            // this lane's bg col
        // B fragment from raw xb: round(xb*w) then exact *-2 in f16
        const float* row = xb + (size_t)bc * DIM + quad * 8;
        const float4 a = ((const float4*)row)[0];
        const float4 b = ((const float4*)row)[1];
        const float v[8] = {a.x,a.y,a.z,a.w,b.x,b.y,b.z,b.w};
        half8 bfrag;
#pragma unroll
        for (int c = 0; c < 8; ++c)
            bfrag[c] = (_Float16)(-2.0f) * (_Float16)(v[c] * wq[c]);

        const float yv  = yb[bc];
        const float b2v = b2l[wid][it * 16 + m];
        float rr[4];
#pragma unroll
        for (int g = 0; g < 4; ++g) rr[g] = rbase[g][it * 16];

        f32x4 cin;
#pragma unroll
        for (int g = 0; g < 4; ++g) cin[g] = q2r[g] + b2v;

        // D = q2 + b2 - 2*dot = d2
        f32x4 d2v = __builtin_amdgcn_mfma_f32_16x16x32_f16(
            afrag, bfrag, cin, 0, 0, 0);

#pragma unroll
        for (int g = 0; g < 4; ++g) {
            float d2 = fmaxf(d2v[g], 0.f);
            float dist = __builtin_amdgcn_sqrtf(d2);
            float e = fmaf(dist, c1, rr[g] * c2);       // log2-space exponent
            float k = __builtin_amdgcn_exp2f(e);
            sk[g] += k;
            sky[g] = fmaf(k, yv, sky[g]);
        }
    }

    // Reduce across the 16 bg-columns (low 4 lane bits), once per wave.
#pragma unroll
    for (int off = 1; off <= 8; off <<= 1) {
#pragma unroll
        for (int g = 0; g < 4; ++g) {
            sk[g]  += __shfl_xor(sk[g],  off, 64);
            sky[g] += __shfl_xor(sky[g], off, 64);
        }
    }
    // Plain float4 stores into this chunk's private slots -- no atomics.
    if (m == 0) {
        f32x4 vk  = {sk[0],  sk[1],  sk[2],  sk[3]};
        f32x4 vky = {sky[0], sky[1], sky[2], sky[3]};
        *(f32x4*)(psk  + (size_t)chunk * NQ + q0 + quad * 4) = vk;
        *(f32x4*)(psky + (size_t)chunk * NQ + q0 + quad * 4) = vky;
    }
}

// Reduce the 32 chunk-partials per query and divide. 8 blocks.
__global__ __launch_bounds__(256) void relnw_finalize(
    const float* __restrict__ psk, const float* __restrict__ psky,
    float* __restrict__ out)
{
    int q = blockIdx.x * 256 + threadIdx.x;
    float sk = 0.f, sky = 0.f;
#pragma unroll
    for (int c = 0; c < NCHUNK; ++c) {
        sk  += psk[(size_t)c * NQ + q];     // coalesced across threads
        sky += psky[(size_t)c * NQ + q];
    }
    out[q] = sky / (sk + 1e-8f);
}

extern "C" void kernel_launch(void* const* d_in, const int* in_sizes, int n_in,
                              void* d_out, int out_size, void* d_ws, size_t ws_size,
                              hipStream_t stream) {
    const float* xb     = (const float*)d_in[0]; // (8192,32)
    const float* yb     = (const float*)d_in[1]; // (8192,)
    const float* xq     = (const float*)d_in[2]; // (2048,32)
    const float* r      = (const float*)d_in[3]; // (2048,8192)
    const float* sigma  = (const float*)d_in[4]; // (1,)
    const float* rscale = (const float*)d_in[5]; // (1,)
    const float* w      = (const float*)d_in[6]; // (32,)
    float* out = (float*)d_out;

    char* ws = (char*)d_ws;
    float* psk  = (float*)(ws + WS_PSK);
    float* psky = (float*)(ws + WS_PSKY);

    dim3 grid(NB / (4 * BG_PER_WAVE), NQ / 16);  // (8, 128) = 1024 blocks
    relnw_main<<<grid, 256, 0, stream>>>(xb, yb, xq, r, sigma, rscale, w,
                                         psk, psky);
    relnw_finalize<<<NQ / 256, 256, 0, stream>>>(psk, psky, out);
}

// Round 10
// 116.443 us; speedup vs baseline: 1.1212x; 1.1212x over previous
//
#include <hip/hip_runtime.h>
#include <math.h>

// Problem constants (from reference setup_inputs)
#define NQ 2048
#define NB 8192
#define DIM 32

#define LOG2E 1.44269504088896340736f

typedef _Float16 half8 __attribute__((ext_vector_type(8)));
typedef float    f32x4 __attribute__((ext_vector_type(4)));

// ---------------- workspace layout (bytes) ----------------
// Partial sums written by plain stores (every slot covered -> no init, no
// atomics, no fences). chunk = blockIdx.x*4 + wave, 64 chunks.
#define NCHUNK 64
#define WS_PSK  0                        // NCHUNK*NQ f32 = 524288 B
#define WS_PSKY (NCHUNK * NQ * 4)        // NCHUNK*NQ f32 = 524288 B
#define WS_Q2   (2 * NCHUNK * NQ * 4)    // NQ f32
#define WS_B2   (WS_Q2 + NQ * 4)         // NB f32
#define WS_XQH  (WS_B2 + NB * 4)         // NQ*DIM f16 (A: rounded xq*w)
#define WS_XBH  (WS_XQH + NQ * DIM * 2)  // NB*DIM f16 (B: -2*rounded(xb*w))

// Pre: convert rows to f16, norms FROM THE ROUNDED VALUES (so the MFMA
// d2 = ||a-b||^2 has no representation-mismatch cancellation). XBh stored
// pre-scaled by -2 (exact) so main's MFMA with C = q2+b2 emits d2 directly.
// R9 lesson: KEEP this staged — fusing prep into main re-pays it per wave
// (~18x the one-time cost; fused main was 43 µs vs ~18 µs staged).
__global__ __launch_bounds__(256) void relnw_pre(
    const float* __restrict__ xq, const float* __restrict__ xb,
    const float* __restrict__ w,
    _Float16* __restrict__ XQh, _Float16* __restrict__ XBh,
    float* __restrict__ q2, float* __restrict__ b2)
{
    const int tid = threadIdx.x;
    const int row = blockIdx.x * 64 + (tid >> 2);
    const int p   = tid & 3;             // 8-elem chunk within the row
    if (row >= NQ + NB) return;

    const float* src; _Float16* dst; float* s2; float scale;
    if (row < NQ) { src = xq + (size_t)row * DIM;
                    dst = XQh + (size_t)row * DIM; s2 = q2 + row; scale = 1.f; }
    else          { int j = row - NQ;
                    src = xb + (size_t)j * DIM;
                    dst = XBh + (size_t)j * DIM;   s2 = b2 + j;   scale = -2.f; }

    const float4 xa  = ((const float4*)src)[p * 2];
    const float4 xbv = ((const float4*)src)[p * 2 + 1];
    const float4 wa  = ((const float4*)w)[p * 2];
    const float4 wb  = ((const float4*)w)[p * 2 + 1];
    const float xs[8]  = {xa.x, xa.y, xa.z, xa.w, xbv.x, xbv.y, xbv.z, xbv.w};
    const float ws_[8] = {wa.x, wa.y, wa.z, wa.w, wb.x, wb.y, wb.z, wb.w};

    half8 h;
    float s = 0.f;
#pragma unroll
    for (int c = 0; c < 8; ++c) {
        float t = xs[c] * ws_[c];
        _Float16 hh = (_Float16)t;       // the rounding
        float th = (float)hh;
        s = fmaf(th, th, s);             // norm of the ROUNDED vector
        h[c] = (_Float16)(th * scale);   // exact scaling
    }
    *(half8*)(dst + p * 8) = h;          // coalesced 16-B store

    s += __shfl_xor(s, 1, 64);
    s += __shfl_xor(s, 2, 64);
    if (p == 0) *s2 = s;
}

// Main: grid (16, 128) = 2048 blocks (8/CU -> 32 waves/CU theoretical; R9
// showed the 1024-block version capped at 16 waves/CU and was latency-bound
// with occupancy 31%). Wave task: 16-query tile x 128-bg chunk = 8 MFMA tiles.
// v_mfma_f32_16x16x32_f16, A = xq*w, B = -2*(xb*w), C = q2+b2 ==> D = d2.
// C/D layout: col = lane&15 (bg), row = (lane>>4)*4 + reg (query).
// R5 lesson: no device fences in-kernel. R7 lesson: no hand prefetch — the
// fully-unrolled loop already lets the scheduler hoist loads.
#define BT_PER_WAVE 8
#define BG_PER_WAVE (BT_PER_WAVE * 16)   // 128

__global__ __launch_bounds__(256) void relnw_main(
    const _Float16* __restrict__ XQh,  // (NQ, DIM)
    const _Float16* __restrict__ XBh,  // (NB, DIM), pre-scaled by -2
    const float* __restrict__ q2,      // (NQ,)
    const float* __restrict__ b2,      // (NB,)
    const float* __restrict__ yb,      // (NB,)
    const float* __restrict__ r,       // (NQ, NB)
    const float* __restrict__ sigma,   // (1,)
    const float* __restrict__ rscale,  // (1,)
    float* __restrict__ psk,           // [NCHUNK][NQ]
    float* __restrict__ psky)          // [NCHUNK][NQ]
{
    const int tid  = threadIdx.x;
    const int lane = tid & 63;
    const int wid  = tid >> 6;
    const int m    = lane & 15;   // A row (query) / B col (bg) / C col (bg)
    const int quad = lane >> 4;   // 0..3

    const int q0     = blockIdx.y * 16;
    const int chunk  = blockIdx.x * 4 + wid;       // 0..63
    const int bstart = chunk * BG_PER_WAVE;

    const float c1 = -LOG2E / sigma[0];   // coeff on dist (log2 space)
    const float c2 =  LOG2E * rscale[0];  // coeff on r

    // A fragment for this wave's 16 queries (fixed across the b-loop)
    const half8 afrag = *(const half8*)(XQh + (size_t)(q0 + m) * DIM + quad * 8);

    float q2r[4];
#pragma unroll
    for (int g = 0; g < 4; ++g) q2r[g] = q2[q0 + quad * 4 + g];

    const _Float16* xbp = XBh + (size_t)(bstart + m) * DIM + quad * 8;

    // r row-base pointers; in-loop r loads are base + compile-time offset
    const float* rbase[4];
#pragma unroll
    for (int g = 0; g < 4; ++g)
        rbase[g] = r + (size_t)(q0 + quad * 4 + g) * NB + bstart + m;

    float sk[4]  = {0.f, 0.f, 0.f, 0.f};
    float sky[4] = {0.f, 0.f, 0.f, 0.f};

#pragma unroll
    for (int it = 0; it < BT_PER_WAVE; ++it) {
        const int bc = bstart + it * 16 + m;            // this lane's bg col
        const half8 bfrag = *(const half8*)(xbp + (size_t)it * 16 * DIM);
        const float yv  = yb[bc];
        const float b2v = b2[bc];
        float rr[4];
#pragma unroll
        for (int g = 0; g < 4; ++g) rr[g] = rbase[g][it * 16];

        f32x4 cin;
#pragma unroll
        for (int g = 0; g < 4; ++g) cin[g] = q2r[g] + b2v;

        // D = q2 + b2 - 2*dot = d2
        f32x4 d2v = __builtin_amdgcn_mfma_f32_16x16x32_f16(
            afrag, bfrag, cin, 0, 0, 0);

#pragma unroll
        for (int g = 0; g < 4; ++g) {
            float d2 = fmaxf(d2v[g], 0.f);
            float dist = __builtin_amdgcn_sqrtf(d2);
            float e = fmaf(dist, c1, rr[g] * c2);       // log2-space exponent
            float k = __builtin_amdgcn_exp2f(e);
            sk[g] += k;
            sky[g] = fmaf(k, yv, sky[g]);
        }
    }

    // Reduce across the 16 bg-columns (low 4 lane bits), once per wave.
#pragma unroll
    for (int off = 1; off <= 8; off <<= 1) {
#pragma unroll
        for (int g = 0; g < 4; ++g) {
            sk[g]  += __shfl_xor(sk[g],  off, 64);
            sky[g] += __shfl_xor(sky[g], off, 64);
        }
    }
    // Plain float4 stores into this chunk's private slots -- no atomics.
    if (m == 0) {
        f32x4 vk  = {sk[0],  sk[1],  sk[2],  sk[3]};
        f32x4 vky = {sky[0], sky[1], sky[2], sky[3]};
        *(f32x4*)(psk  + (size_t)chunk * NQ + q0 + quad * 4) = vk;
        *(f32x4*)(psky + (size_t)chunk * NQ + q0 + quad * 4) = vky;
    }
}

// Reduce the 64 chunk-partials per query and divide. 8 blocks.
__global__ __launch_bounds__(256) void relnw_finalize(
    const float* __restrict__ psk, const float* __restrict__ psky,
    float* __restrict__ out)
{
    int q = blockIdx.x * 256 + threadIdx.x;
    float sk = 0.f, sky = 0.f;
#pragma unroll 8
    for (int c = 0; c < NCHUNK; ++c) {
        sk  += psk[(size_t)c * NQ + q];     // coalesced across threads
        sky += psky[(size_t)c * NQ + q];
    }
    out[q] = sky / (sk + 1e-8f);
}

extern "C" void kernel_launch(void* const* d_in, const int* in_sizes, int n_in,
                              void* d_out, int out_size, void* d_ws, size_t ws_size,
                              hipStream_t stream) {
    const float* xb     = (const float*)d_in[0]; // (8192,32)
    const float* yb     = (const float*)d_in[1]; // (8192,)
    const float* xq     = (const float*)d_in[2]; // (2048,32)
    const float* r      = (const float*)d_in[3]; // (2048,8192)
    const float* sigma  = (const float*)d_in[4]; // (1,)
    const float* rscale = (const float*)d_in[5]; // (1,)
    const float* w      = (const float*)d_in[6]; // (32,)
    float* out = (float*)d_out;

    char* ws = (char*)d_ws;
    float*    psk  = (float*)(ws + WS_PSK);
    float*    psky = (float*)(ws + WS_PSKY);
    float*    q2   = (float*)(ws + WS_Q2);
    float*    b2   = (float*)(ws + WS_B2);
    _Float16* XQh  = (_Float16*)(ws + WS_XQH);
    _Float16* XBh  = (_Float16*)(ws + WS_XBH);

    relnw_pre<<<(NQ + NB) / 64, 256, 0, stream>>>(xq, xb, w, XQh, XBh, q2, b2);

    dim3 grid(NB / (4 * BG_PER_WAVE), NQ / 16);  // (16, 128) = 2048 blocks
    relnw_main<<<grid, 256, 0, stream>>>(XQh, XBh, q2, b2, yb, r, sigma, rscale,
                                         psk, psky);

    relnw_finalize<<<NQ / 256, 256, 0, stream>>>(psk, psky, out);
}